// Round 4
// baseline (33464.771 us; speedup 1.0000x reference)
//
#include <hip/hip_runtime.h>
#include <math.h>

// ---------------------------------------------------------------------------
// Persistent-RNN LSTM v4 for MI355X — L2-cached h broadcast + targeted inv.
//   B=128, T=512, IN=64, H=1024, 2 layers, head OUT=1 on last step.
//
// vs v3 (29 ms; all h loads were sc1/MALL-path at ~1.1 TB/s effective):
//  - h stores: agent-scope (sc1) atomic stores, write-through to MALL,
//    widened to 8 B via LDS staging (threads 0..255 store 64 rows x 16 B).
//  - h loads: PLAIN cached loads (L1/L2), full compiler pipelining.
//  - Coherence: per-iter `buffer_inv sc0` + `buffer_inv sc1` (invalidate
//    clean L1/L2 lines) after the flag barrier, before any h load. Nothing
//    dirty lives in L2 (h is write-through; weights/xT read-only), so inv
//    is cheap — no wbl2 ever.
//  - Distributed flag barrier unchanged (v3-proven).
// Decomposition unchanged: 128 col-groups x 2 batch-groups; WG owns 8 h-cols
// (32 gate rows = 2 B-tiles) x 64 batch rows (4 A-tiles); zero-dup k-split
// over 8 waves; LDS atomicAdd k-reduction; 1 cell/thread/layer.
// ---------------------------------------------------------------------------

#define Hd 1024
#define Bd 128
#define Td 512
#define INd 64
#define NWG 256
#define NTHR 512

typedef _Float16 f16;
typedef _Float16 half8 __attribute__((ext_vector_type(8)));
typedef float f32x4 __attribute__((ext_vector_type(4)));

// ---------------- init: bi0/bi1, zero h buffers (both parities), flags ------
__global__ __launch_bounds__(512) void init_state(
    const float* __restrict__ bnd, const float* __restrict__ Wb0,
    const float* __restrict__ bb0, const float* __restrict__ Wb1,
    const float* __restrict__ bb1,
    float* __restrict__ bi0, float* __restrict__ bi1,
    f16* __restrict__ h0buf, f16* __restrict__ h1buf,
    unsigned int* __restrict__ flags)
{
    int idx = blockIdx.x * 512 + threadIdx.x;   // [0, B*H)
    int b = idx >> 10;
    int h = idx & 1023;
    float b0v = bnd[b * 2 + 0], b1v = bnd[b * 2 + 1];
    bi0[idx] = b0v * Wb0[h * 2 + 0] + b1v * Wb0[h * 2 + 1] + bb0[h];
    bi1[idx] = b0v * Wb1[h * 2 + 0] + b1v * Wb1[h * 2 + 1] + bb1[h];
    h0buf[idx] = (f16)0.f;  h0buf[idx + Bd * Hd] = (f16)0.f;
    h1buf[idx] = (f16)0.f;  h1buf[idx + Bd * Hd] = (f16)0.f;
    if (idx < NWG) flags[idx] = 0u;
}

// ---------------- transpose x [B,T,IN] f32 -> xT [T,B,IN] f16 ---------------
__global__ __launch_bounds__(512) void xpose(
    const float* __restrict__ x, f16* __restrict__ xT)
{
    int idx = blockIdx.x * 512 + threadIdx.x;   // [0, B*T*IN)
    int b = idx >> 15;           // T*IN = 32768
    int t = (idx >> 6) & 511;
    int i = idx & 63;
    xT[((size_t)t * Bd + b) * INd + i] = (f16)x[idx];
}

// invalidate clean L1 + L2 lines; drain so later loads refetch fresh data
__device__ __forceinline__ void inv_caches() {
    asm volatile("buffer_inv sc0\n\t"
                 "buffer_inv sc1\n\t"
                 "s_waitcnt vmcnt(0)" ::: "memory");
}

// ---------------- persistent LSTM ----------------
__global__ __launch_bounds__(NTHR, 2) void lstm_persist(
    const f16* __restrict__ xT,
    f16* __restrict__ h0b_, f16* __restrict__ h1b_,
    const float* __restrict__ bi0, const float* __restrict__ bi1,
    const float* __restrict__ Wx0, const float* __restrict__ bx0,
    const float* __restrict__ Uh0, const float* __restrict__ bh0,
    const float* __restrict__ Wx1, const float* __restrict__ bx1,
    const float* __restrict__ Uh1, const float* __restrict__ bh1,
    const float* __restrict__ fcW, const float* __restrict__ fcb,
    float* __restrict__ out, unsigned int* __restrict__ flags)
{
    const int tid  = threadIdx.x;
    const int w    = tid >> 6;        // wave 0..7
    const int lane = tid & 63;
    const int n    = lane & 15;       // MFMA col index
    const int q    = lane >> 4;       // quad 0..3
    const int wg   = blockIdx.x;
    const int cg   = wg & 127;        // col group  -> cols Cb..Cb+7
    const int bg   = wg >> 7;         // batch group-> rows Rb..Rb+63
    const int Cb   = cg * 8;
    const int Rb   = bg * 64;
    const size_t S2 = (size_t)Bd * Hd;

    __shared__ float ACC[2][8][256];   // [layer][tile a*2+bt][(q*4+r)*16+n]
    __shared__ f16 HST[2][64][8];      // staged h outputs (row-major, 16 B/row)
    __shared__ float red[8];

    // B-fragment row j = bt*16+n -> gate (j>>3), col (j&7)
    int grow[2];
    #pragma unroll
    for (int bt = 0; bt < 2; ++bt) {
        int j = bt * 16 + n;
        grow[bt] = (j >> 3) * Hd + Cb + (j & 7);
    }

    // ---- L1 weights: wave w holds k-frags (w<4: Wx1/h0 half, w>=4: Uh1/h1
    //      half), both B-tiles. 64 VGPRs. Zero duplication. ----
    half8 wL1[8][2];
    {
        const float* Wsrc = (w < 4) ? Wx1 : Uh1;
        const int kbase = (w < 4 ? w : w - 4) * 256;
        #pragma unroll
        for (int kk = 0; kk < 8; ++kk) {
            #pragma unroll
            for (int bt = 0; bt < 2; ++bt) {
                const float* rp = Wsrc + (size_t)grow[bt] * Hd + kbase + kk * 32 + q * 8;
                half8 hv;
                #pragma unroll
                for (int j = 0; j < 8; ++j) hv[j] = (f16)rp[j];
                wL1[kk][bt] = hv;
            }
        }
    }
    // ---- L0 weights: waves 0-3 hold Uh0 k-frags; waves 6,7 hold Wx0 ----
    half8 wL0[8][2];
    half8 wX[2];
    if (w < 4) {
        #pragma unroll
        for (int kk = 0; kk < 8; ++kk) {
            #pragma unroll
            for (int bt = 0; bt < 2; ++bt) {
                const float* rp = Uh0 + (size_t)grow[bt] * Hd + w * 256 + kk * 32 + q * 8;
                half8 hv;
                #pragma unroll
                for (int j = 0; j < 8; ++j) hv[j] = (f16)rp[j];
                wL0[kk][bt] = hv;
            }
        }
    } else if (w >= 6) {
        #pragma unroll
        for (int bt = 0; bt < 2; ++bt) {
            const float* rp = Wx0 + (size_t)grow[bt] * INd + (w - 6) * 32 + q * 8;
            half8 hv;
            #pragma unroll
            for (int j = 0; j < 8; ++j) hv[j] = (f16)rp[j];
            wX[bt] = hv;
        }
    }

    // ---- per-thread cell state: cell (row=Rb+tid>>3, col=Cb+tid&7) ----
    const int crow = tid >> 3, ccol = tid & 7;
    const int gR = Rb + crow, gC = Cb + ccol;
    float gb0[4], gb1[4];
    #pragma unroll
    for (int g = 0; g < 4; ++g) {
        gb0[g] = bx0[g * Hd + gC] + bh0[g * Hd + gC];
        gb1[g] = bx1[g * Hd + gC] + bh1[g * Hd + gC];
    }
    const float ba0 = bi0[(size_t)gR * Hd + gC];
    const float ba1 = bi1[(size_t)gR * Hd + gC];
    float c0s = 0.f, c1s = 0.f;
    const int ca = crow >> 4, crr = crow & 15;

    // ---- main sequence: iter s computes layer1(s) and layer0(s+1) ----
    for (int s = -1; s <= 511; ++s) {
        const bool doL0 = (s < 511), doL1 = (s >= 0);
        const f16* h0r = h0b_ + (size_t)(s & 1) * S2;         // h0(s)
        f16*       h0w = h0b_ + (size_t)((s + 1) & 1) * S2;   // h0(s+1)
        const f16* h1r = h1b_ + (size_t)((s - 1) & 1) * S2;   // h1(s-1)
        f16*       h1w = h1b_ + (size_t)(s & 1) * S2;         // h1(s)

        // drop stale clean h lines from L1/L2 (producers wrote through to
        // MALL; flags barrier of previous iter guarantees they're there)
        inv_caches();

        // zero ACC
        {
            float* az = &ACC[0][0][0];
            #pragma unroll
            for (int i = 0; i < 8; ++i) az[tid + i * 512] = 0.f;
        }

        f32x4 aL1[4][2], aL0[4][2];
        #pragma unroll
        for (int a = 0; a < 4; ++a)
            #pragma unroll
            for (int bt = 0; bt < 2; ++bt) {
                aL1[a][bt] = (f32x4){0.f, 0.f, 0.f, 0.f};
                aL0[a][bt] = (f32x4){0.f, 0.f, 0.f, 0.f};
            }

        if (w < 4) {
            // A = h0(s) rows Rb+a*16+n, cols w*256+kk*32+q*8 (plain cached);
            // feeds BOTH layer1(s) k-half0 and layer0(s+1) h-part.
            #pragma unroll
            for (int kk = 0; kk < 8; ++kk) {
                half8 Af[4];
                #pragma unroll
                for (int a = 0; a < 4; ++a)
                    Af[a] = *(const half8*)(h0r + (size_t)(Rb + a * 16 + n) * Hd
                                            + w * 256 + kk * 32 + q * 8);
                if (doL1) {
                    #pragma unroll
                    for (int a = 0; a < 4; ++a)
                        #pragma unroll
                        for (int bt = 0; bt < 2; ++bt)
                            aL1[a][bt] = __builtin_amdgcn_mfma_f32_16x16x32_f16(
                                Af[a], wL1[kk][bt], aL1[a][bt], 0, 0, 0);
                }
                if (doL0) {
                    #pragma unroll
                    for (int a = 0; a < 4; ++a)
                        #pragma unroll
                        for (int bt = 0; bt < 2; ++bt)
                            aL0[a][bt] = __builtin_amdgcn_mfma_f32_16x16x32_f16(
                                Af[a], wL0[kk][bt], aL0[a][bt], 0, 0, 0);
                }
            }
        } else {
            if (doL1) {
                // A = h1(s-1), cols (w-4)*256+kk*32+q*8 (plain cached)
                #pragma unroll
                for (int kk = 0; kk < 8; ++kk) {
                    half8 Af[4];
                    #pragma unroll
                    for (int a = 0; a < 4; ++a)
                        Af[a] = *(const half8*)(h1r + (size_t)(Rb + a * 16 + n) * Hd
                                                + (w - 4) * 256 + kk * 32 + q * 8);
                    #pragma unroll
                    for (int a = 0; a < 4; ++a)
                        #pragma unroll
                        for (int bt = 0; bt < 2; ++bt)
                            aL1[a][bt] = __builtin_amdgcn_mfma_f32_16x16x32_f16(
                                Af[a], wL1[kk][bt], aL1[a][bt], 0, 0, 0);
                }
            }
            if (w >= 6 && doL0) {
                // x-projection: A = xT[s+1] (read-only)
                const f16* xb = xT + (size_t)(s + 1) * Bd * INd;
                #pragma unroll
                for (int a = 0; a < 4; ++a) {
                    half8 Af = *(const half8*)(xb + (size_t)(Rb + a * 16 + n) * INd
                                               + (w - 6) * 32 + q * 8);
                    #pragma unroll
                    for (int bt = 0; bt < 2; ++bt)
                        aL0[a][bt] = __builtin_amdgcn_mfma_f32_16x16x32_f16(
                            Af, wX[bt], aL0[a][bt], 0, 0, 0);
                }
            }
        }

        __syncthreads();   // ACC zero + all partials ready

        // ---- k-reduction via LDS float atomics ----
        if (doL1) {
            #pragma unroll
            for (int a = 0; a < 4; ++a)
                #pragma unroll
                for (int bt = 0; bt < 2; ++bt)
                    #pragma unroll
                    for (int r = 0; r < 4; ++r)
                        atomicAdd(&ACC[1][a * 2 + bt][(q * 4 + r) * 16 + n],
                                  aL1[a][bt][r]);
        }
        if (doL0 && (w < 4 || w >= 6)) {
            #pragma unroll
            for (int a = 0; a < 4; ++a)
                #pragma unroll
                for (int bt = 0; bt < 2; ++bt)
                    #pragma unroll
                    for (int r = 0; r < 4; ++r)
                        atomicAdd(&ACC[0][a * 2 + bt][(q * 4 + r) * 16 + n],
                                  aL0[a][bt][r]);
        }
        __syncthreads();

        // ---- cell updates -> stage h into LDS ----
        if (doL0) {
            float ip = ACC[0][ca * 2 + 0][crr * 16 + ccol]     + gb0[0];
            float fp = ACC[0][ca * 2 + 0][crr * 16 + 8 + ccol] + gb0[1] + ba0;
            float op = ACC[0][ca * 2 + 1][crr * 16 + ccol]     + gb0[2];
            float gp = ACC[0][ca * 2 + 1][crr * 16 + 8 + ccol] + gb0[3];
            float I = 1.f / (1.f + expf(-ip));
            float F = 1.f / (1.f + expf(-fp));
            float O = 1.f / (1.f + expf(-op));
            float G = tanhf(gp);
            c0s = F * c0s + I * G;
            HST[0][crow][ccol] = (f16)(O * tanhf(c0s));
        }
        if (doL1) {
            float ip = ACC[1][ca * 2 + 0][crr * 16 + ccol]     + gb1[0];
            float fp = ACC[1][ca * 2 + 0][crr * 16 + 8 + ccol] + gb1[1] + ba1;
            float op = ACC[1][ca * 2 + 1][crr * 16 + ccol]     + gb1[2];
            float gp = ACC[1][ca * 2 + 1][crr * 16 + 8 + ccol] + gb1[3];
            float I = 1.f / (1.f + expf(-ip));
            float F = 1.f / (1.f + expf(-fp));
            float O = 1.f / (1.f + expf(-op));
            float G = tanhf(gp);
            c1s = F * c1s + I * G;
            HST[1][crow][ccol] = (f16)(O * tanhf(c1s));
        }
        __syncthreads();   // HST complete; ACC reads done

        // ---- wide write-through stores: 8 B agent-scope, 2 per row ----
        if (tid < 256) {
            int L = tid >> 7, idx = tid & 127, row = idx >> 1, hh = idx & 1;
            bool go = L ? doL1 : doL0;
            if (go) {
                unsigned long long v =
                    *(const unsigned long long*)&HST[L][row][hh * 4];
                f16* dst = (L ? h1w : h0w) + (size_t)(Rb + row) * Hd + Cb + hh * 4;
                __hip_atomic_store((unsigned long long*)dst, v,
                                   __ATOMIC_RELAXED, __HIP_MEMORY_SCOPE_AGENT);
            }
        }
        asm volatile("s_waitcnt vmcnt(0)" ::: "memory");  // stores at MALL
        __syncthreads();                                  // whole WG drained

        // ---- distributed flag barrier ----
        const unsigned target = (unsigned)(s + 2);
        if (tid == 0)
            __hip_atomic_store(&flags[wg], target,
                               __ATOMIC_RELAXED, __HIP_MEMORY_SCOPE_AGENT);
        if (w == 0) {
            while (true) {
                unsigned f0 = __hip_atomic_load(&flags[lane],
                                 __ATOMIC_RELAXED, __HIP_MEMORY_SCOPE_AGENT);
                unsigned f1 = __hip_atomic_load(&flags[64 + lane],
                                 __ATOMIC_RELAXED, __HIP_MEMORY_SCOPE_AGENT);
                unsigned f2 = __hip_atomic_load(&flags[128 + lane],
                                 __ATOMIC_RELAXED, __HIP_MEMORY_SCOPE_AGENT);
                unsigned f3 = __hip_atomic_load(&flags[192 + lane],
                                 __ATOMIC_RELAXED, __HIP_MEMORY_SCOPE_AGENT);
                bool ok = (f0 >= target) && (f1 >= target) &&
                          (f2 >= target) && (f3 >= target);
                if (__all(ok)) break;
                __builtin_amdgcn_s_sleep(2);
            }
        }
        asm volatile("" ::: "memory");
        __syncthreads();
    }

    // ---- fc head: out[b] = fcW . h1(511)[b] + fcb (h1 slot 1) ----
    inv_caches();   // h1(511) lines may be stale in local caches
    if (wg < Bd) {
        float partial = 0.f;
        if (tid < 256) {
            const f16* hrow = h1b_ + S2 + (size_t)wg * Hd + tid * 4;
            f16 h0v = hrow[0], h1v = hrow[1], h2v = hrow[2], h3v = hrow[3];
            const float* fw = fcW + tid * 4;
            partial = (float)h0v * fw[0] + (float)h1v * fw[1]
                    + (float)h2v * fw[2] + (float)h3v * fw[3];
        }
        #pragma unroll
        for (int off = 32; off > 0; off >>= 1) partial += __shfl_down(partial, off);
        if (lane == 0) red[w] = partial;
        __syncthreads();
        if (tid == 0) {
            float t = 0.f;
            #pragma unroll
            for (int i = 0; i < 8; ++i) t += red[i];
            out[wg] = t + fcb[0];
        }
    }
}

// ---------------------------------------------------------------------------
extern "C" void kernel_launch(void* const* d_in, const int* in_sizes, int n_in,
                              void* d_out, int out_size, void* d_ws, size_t ws_size,
                              hipStream_t stream) {
    const float* x        = (const float*)d_in[0];
    const float* boundary = (const float*)d_in[1];
    const float* Wx0      = (const float*)d_in[2];
    const float* bx0      = (const float*)d_in[3];
    const float* Uh0      = (const float*)d_in[4];
    const float* bh0      = (const float*)d_in[5];
    const float* Wb0      = (const float*)d_in[6];
    const float* bb0      = (const float*)d_in[7];
    const float* Wx1      = (const float*)d_in[8];
    const float* bx1      = (const float*)d_in[9];
    const float* Uh1      = (const float*)d_in[10];
    const float* bh1      = (const float*)d_in[11];
    const float* Wb1      = (const float*)d_in[12];
    const float* bb1      = (const float*)d_in[13];
    const float* fcW      = (const float*)d_in[14];
    const float* fcb      = (const float*)d_in[15];
    float* out = (float*)d_out;

    // workspace layout (bytes)
    char* ws = (char*)d_ws;
    f16*   xT    = (f16*)(ws);                       // 8,388,608
    f16*   h0buf = (f16*)(ws + 8388608);             //   524,288 (2 parities)
    f16*   h1buf = (f16*)(ws + 8912896);             //   524,288
    float* bi0   = (float*)(ws + 9437184);           //   524,288
    float* bi1   = (float*)(ws + 9961472);           //   524,288
    unsigned int* flags = (unsigned int*)(ws + 10485760);  // 1 KB

    init_state<<<256, 512, 0, stream>>>(boundary, Wb0, bb0, Wb1, bb1,
                                        bi0, bi1, h0buf, h1buf, flags);
    xpose<<<8192, 512, 0, stream>>>(x, xT);

    void* args[] = {
        (void*)&xT, (void*)&h0buf, (void*)&h1buf, (void*)&bi0, (void*)&bi1,
        (void*)&Wx0, (void*)&bx0, (void*)&Uh0, (void*)&bh0,
        (void*)&Wx1, (void*)&bx1, (void*)&Uh1, (void*)&bh1,
        (void*)&fcW, (void*)&fcb, (void*)&out, (void*)&flags
    };
    hipLaunchCooperativeKernel((void*)lstm_persist, dim3(NWG), dim3(NTHR),
                               args, 0, stream);
}

// Round 5
// 28768.350 us; speedup vs baseline: 1.1632x; 1.1632x over previous
//
#include <hip/hip_runtime.h>
#include <math.h>

// ---------------------------------------------------------------------------
// Per-step graph-launched LSTM v5 for MI355X.
//   B=128, T=512, IN=64, H=1024, 2 layers, head OUT=1 on last step.
//
// vs v2-v4 (persistent cooperative kernel): every in-kernel coherence scheme
// (threadfence, sc1 loads, buffer_inv) cost 30-65 us/iter. v5 uses 513
// ordinary kernel launches captured in the harness's graph; the command
// processor's dispatch-boundary acquire/release handles cross-XCD coherence
// once per kernel, efficiently.
//
// Kernel s (s = -1..511) computes:
//   layer1(s):   g1 = h0(s)@Wx1^T + h1(s-1)@Uh1^T + biases -> h1(s), c1
//   layer0(s+1): g0 = x(s+1)@Wx0^T + h0(s)@Uh0^T + biases  -> h0(s+1), c0
// Both read only state produced by the PREVIOUS kernel -> no intra-kernel
// grid dependency. Blocks 0..255: layer1. Blocks 256..511: layer0.
//
// Intra-block decomposition (v4-proven, absmax 1.2e-4): block owns 8 h-cols
// (32 gate rows = 2 B-tiles) x 64 batch rows (4 A-tiles); K split over 8
// waves (256-wide slices); LDS atomicAdd k-reduction; 1 cell/thread.
// Weights stream as f32 + in-flight cvt to f16. h-state stored f16;
// c-state global fp32 (RMW by owning thread).
// ---------------------------------------------------------------------------

#define Hd 1024
#define Bd 128
#define Td 512
#define INd 64

typedef _Float16 f16;
typedef _Float16 half8 __attribute__((ext_vector_type(8)));
typedef float f32x4 __attribute__((ext_vector_type(4)));

__device__ __forceinline__ half8 ldcvt8(const float* p) {
    float4 a = *(const float4*)p;
    float4 b = *(const float4*)(p + 4);
    half8 h;
    h[0] = (f16)a.x; h[1] = (f16)a.y; h[2] = (f16)a.z; h[3] = (f16)a.w;
    h[4] = (f16)b.x; h[5] = (f16)b.y; h[6] = (f16)b.z; h[7] = (f16)b.w;
    return h;
}

// ---------------- init: bi0/bi1, zero c-state and the read-first h slots ----
__global__ __launch_bounds__(512) void init_state(
    const float* __restrict__ bnd, const float* __restrict__ Wb0,
    const float* __restrict__ bb0, const float* __restrict__ Wb1,
    const float* __restrict__ bb1,
    float* __restrict__ bi0, float* __restrict__ bi1,
    float* __restrict__ c0g, float* __restrict__ c1g,
    f16* __restrict__ h0buf, f16* __restrict__ h1buf)
{
    int idx = blockIdx.x * 512 + threadIdx.x;   // [0, B*H)
    int b = idx >> 10;
    int h = idx & 1023;
    float b0v = bnd[b * 2 + 0], b1v = bnd[b * 2 + 1];
    bi0[idx] = b0v * Wb0[h * 2 + 0] + b1v * Wb0[h * 2 + 1] + bb0[h];
    bi1[idx] = b0v * Wb1[h * 2 + 0] + b1v * Wb1[h * 2 + 1] + bb1[h];
    c0g[idx] = 0.f;
    c1g[idx] = 0.f;
    // h0(-1) lives in slot (-1)&1 = 1; h1(-1) in slot 1. Slot 0 is written
    // before first read.
    h0buf[idx + Bd * Hd] = (f16)0.f;
    h1buf[idx + Bd * Hd] = (f16)0.f;
}

// ---------------- one pipelined step ----------------
__global__ __launch_bounds__(512, 4) void step_kernel(
    int s,
    const float* __restrict__ x,     // [B,T,IN] f32
    f16* __restrict__ h0buf, f16* __restrict__ h1buf,
    float* __restrict__ c0g, float* __restrict__ c1g,
    const float* __restrict__ bi0, const float* __restrict__ bi1,
    const float* __restrict__ Wx0, const float* __restrict__ bx0,
    const float* __restrict__ Uh0, const float* __restrict__ bh0,
    const float* __restrict__ Wx1, const float* __restrict__ bx1,
    const float* __restrict__ Uh1, const float* __restrict__ bh1)
{
    const int bid = blockIdx.x;
    const bool isL1 = (bid < 256);
    if (isL1 && s < 0) return;        // no layer1 at s=-1
    if (!isL1 && s >= 511) return;    // no layer0 at s=511

    const int tid  = threadIdx.x;
    const int w    = tid >> 6;        // wave 0..7
    const int lane = tid & 63;
    const int n    = lane & 15;
    const int q    = lane >> 4;
    const int id2  = isL1 ? bid : bid - 256;
    const int cg   = id2 & 127;       // col group  -> cols Cb..Cb+7
    const int bg   = id2 >> 7;        // batch group-> rows Rb..Rb+63
    const int Cb   = cg * 8;
    const int Rb   = bg * 64;
    const size_t S2 = (size_t)Bd * Hd;

    const f16* h0r = h0buf + (size_t)(s & 1) * S2;          // h0(s)
    const f16* h1r = h1buf + (size_t)((s - 1) & 1) * S2;    // h1(s-1)
    f16* h1w = h1buf + (size_t)(s & 1) * S2;                // h1(s)
    f16* h0w = h0buf + (size_t)((s + 1) & 1) * S2;          // h0(s+1)

    __shared__ float ACC[8][256];     // [tile a*2+bt][(q*4+r)*16+n] : 8 KB
    __shared__ f16 HST[64][8];        // staged h outputs

    // B-fragment row j = bt*16+n -> weight row (gate*H + col)
    int grow[2];
    #pragma unroll
    for (int bt = 0; bt < 2; ++bt) {
        int j = bt * 16 + n;
        grow[bt] = (j >> 3) * Hd + Cb + (j & 7);
    }

    // zero ACC
    {
        float* az = &ACC[0][0];
        #pragma unroll
        for (int i = 0; i < 4; ++i) az[tid + i * 512] = 0.f;
    }
    __syncthreads();

    f32x4 acc[4][2];
    #pragma unroll
    for (int a = 0; a < 4; ++a) {
        acc[a][0] = (f32x4){0.f, 0.f, 0.f, 0.f};
        acc[a][1] = (f32x4){0.f, 0.f, 0.f, 0.f};
    }

    bool contrib = false;
    if (isL1) {
        // K = 2048: waves 0-3 cover h0(s)@Wx1 k=0..1023 (256-slices);
        //           waves 4-7 cover h1(s-1)@Uh1.
        const f16*  hsrc = (w < 4) ? h0r : h1r;
        const float* Wsrc = (w < 4) ? Wx1 : Uh1;
        const int kbase = (w & 3) * 256;
        #pragma unroll
        for (int kk = 0; kk < 8; ++kk) {
            const int ko = kbase + kk * 32 + q * 8;
            half8 Af[4];
            #pragma unroll
            for (int a = 0; a < 4; ++a)
                Af[a] = *(const half8*)(hsrc + (size_t)(Rb + a * 16 + n) * Hd + ko);
            half8 B0 = ldcvt8(Wsrc + (size_t)grow[0] * Hd + ko);
            half8 B1 = ldcvt8(Wsrc + (size_t)grow[1] * Hd + ko);
            #pragma unroll
            for (int a = 0; a < 4; ++a) {
                acc[a][0] = __builtin_amdgcn_mfma_f32_16x16x32_f16(Af[a], B0, acc[a][0], 0, 0, 0);
                acc[a][1] = __builtin_amdgcn_mfma_f32_16x16x32_f16(Af[a], B1, acc[a][1], 0, 0, 0);
            }
        }
        contrib = true;
    } else {
        if (w < 4) {
            // h0(s) @ Uh0, k=0..1023 in 256-slices
            const int kbase = w * 256;
            #pragma unroll
            for (int kk = 0; kk < 8; ++kk) {
                const int ko = kbase + kk * 32 + q * 8;
                half8 Af[4];
                #pragma unroll
                for (int a = 0; a < 4; ++a)
                    Af[a] = *(const half8*)(h0r + (size_t)(Rb + a * 16 + n) * Hd + ko);
                half8 B0 = ldcvt8(Uh0 + (size_t)grow[0] * Hd + ko);
                half8 B1 = ldcvt8(Uh0 + (size_t)grow[1] * Hd + ko);
                #pragma unroll
                for (int a = 0; a < 4; ++a) {
                    acc[a][0] = __builtin_amdgcn_mfma_f32_16x16x32_f16(Af[a], B0, acc[a][0], 0, 0, 0);
                    acc[a][1] = __builtin_amdgcn_mfma_f32_16x16x32_f16(Af[a], B1, acc[a][1], 0, 0, 0);
                }
            }
            contrib = true;
        } else if (w >= 6) {
            // x(s+1) @ Wx0, k = (w-6)*32 .. +31
            const int ko = (w - 6) * 32 + q * 8;
            half8 B0 = ldcvt8(Wx0 + (size_t)grow[0] * INd + ko);
            half8 B1 = ldcvt8(Wx0 + (size_t)grow[1] * INd + ko);
            #pragma unroll
            for (int a = 0; a < 4; ++a) {
                half8 Af = ldcvt8(x + ((size_t)(Rb + a * 16 + n) * Td + (s + 1)) * INd + ko);
                acc[a][0] = __builtin_amdgcn_mfma_f32_16x16x32_f16(Af, B0, acc[a][0], 0, 0, 0);
                acc[a][1] = __builtin_amdgcn_mfma_f32_16x16x32_f16(Af, B1, acc[a][1], 0, 0, 0);
            }
            contrib = true;
        }
    }

    // ---- k-reduction via LDS float atomics ----
    if (contrib) {
        #pragma unroll
        for (int a = 0; a < 4; ++a)
            #pragma unroll
            for (int bt = 0; bt < 2; ++bt)
                #pragma unroll
                for (int r = 0; r < 4; ++r)
                    atomicAdd(&ACC[a * 2 + bt][(q * 4 + r) * 16 + n], acc[a][bt][r]);
    }
    __syncthreads();

    // ---- cell update: one cell (row=Rb+tid>>3, col=Cb+tid&7) per thread ----
    {
        const int crow = tid >> 3, ccol = tid & 7;
        const int gR = Rb + crow, gC = Cb + ccol;
        const int ca = crow >> 4, crr = crow & 15;
        const float* bx = isL1 ? bx1 : bx0;
        const float* bh = isL1 ? bh1 : bh0;
        const float* bi = isL1 ? bi1 : bi0;
        float* cst = isL1 ? c1g : c0g;

        float ip = ACC[ca * 2 + 0][crr * 16 + ccol]     + bx[0 * Hd + gC] + bh[0 * Hd + gC];
        float fp = ACC[ca * 2 + 0][crr * 16 + 8 + ccol] + bx[1 * Hd + gC] + bh[1 * Hd + gC]
                 + bi[(size_t)gR * Hd + gC];
        float op = ACC[ca * 2 + 1][crr * 16 + ccol]     + bx[2 * Hd + gC] + bh[2 * Hd + gC];
        float gp = ACC[ca * 2 + 1][crr * 16 + 8 + ccol] + bx[3 * Hd + gC] + bh[3 * Hd + gC];
        float I = 1.f / (1.f + expf(-ip));
        float F = 1.f / (1.f + expf(-fp));
        float O = 1.f / (1.f + expf(-op));
        float G = tanhf(gp);
        float c = F * cst[(size_t)gR * Hd + gC] + I * G;
        cst[(size_t)gR * Hd + gC] = c;
        HST[crow][ccol] = (f16)(O * tanhf(c));
    }
    __syncthreads();

    // ---- wide h stores: 8 B each, threads 0..127 ----
    if (tid < 128) {
        int row = tid >> 1, hh = tid & 1;
        unsigned long long v = *(const unsigned long long*)&HST[row][hh * 4];
        f16* dst = (isL1 ? h1w : h0w) + (size_t)(Rb + row) * Hd + Cb + hh * 4;
        *(unsigned long long*)dst = v;
    }
}

// ---------------- fc head: out[b] = fcW . h1(511)[b] + fcb ----------------
__global__ __launch_bounds__(256) void fc_kernel(
    const f16* __restrict__ h1,   // [B,H] f16 (slot 1)
    const float* __restrict__ fcW,
    const float* __restrict__ fcb,
    float* __restrict__ out)
{
    int b = blockIdx.x;
    int tid = threadIdx.x;
    const f16* hrow = h1 + (size_t)b * Hd + tid * 4;
    const float* fw = fcW + tid * 4;
    float sum = (float)hrow[0] * fw[0] + (float)hrow[1] * fw[1]
              + (float)hrow[2] * fw[2] + (float)hrow[3] * fw[3];
    #pragma unroll
    for (int off = 32; off > 0; off >>= 1) sum += __shfl_down(sum, off, 64);
    __shared__ float ls[4];
    if ((tid & 63) == 0) ls[tid >> 6] = sum;
    __syncthreads();
    if (tid == 0) out[b] = ls[0] + ls[1] + ls[2] + ls[3] + fcb[0];
}

// ---------------------------------------------------------------------------
extern "C" void kernel_launch(void* const* d_in, const int* in_sizes, int n_in,
                              void* d_out, int out_size, void* d_ws, size_t ws_size,
                              hipStream_t stream) {
    const float* x        = (const float*)d_in[0];
    const float* boundary = (const float*)d_in[1];
    const float* Wx0      = (const float*)d_in[2];
    const float* bx0      = (const float*)d_in[3];
    const float* Uh0      = (const float*)d_in[4];
    const float* bh0      = (const float*)d_in[5];
    const float* Wb0      = (const float*)d_in[6];
    const float* bb0      = (const float*)d_in[7];
    const float* Wx1      = (const float*)d_in[8];
    const float* bx1      = (const float*)d_in[9];
    const float* Uh1      = (const float*)d_in[10];
    const float* bh1      = (const float*)d_in[11];
    const float* Wb1      = (const float*)d_in[12];
    const float* bb1      = (const float*)d_in[13];
    const float* fcW      = (const float*)d_in[14];
    const float* fcb      = (const float*)d_in[15];
    float* out = (float*)d_out;

    // workspace layout (bytes); total 3 MB
    char* ws = (char*)d_ws;
    f16*   h0buf = (f16*)(ws);                  // 2 slots x 256 KB
    f16*   h1buf = (f16*)(ws + 524288);         // 2 slots x 256 KB
    float* c0g   = (float*)(ws + 1048576);      // 512 KB
    float* c1g   = (float*)(ws + 1572864);      // 512 KB
    float* bi0   = (float*)(ws + 2097152);      // 512 KB
    float* bi1   = (float*)(ws + 2621440);      // 512 KB

    init_state<<<256, 512, 0, stream>>>(boundary, Wb0, bb0, Wb1, bb1,
                                        bi0, bi1, c0g, c1g, h0buf, h1buf);

    for (int s = -1; s <= 511; ++s) {
        step_kernel<<<512, 512, 0, stream>>>(s, x, h0buf, h1buf, c0g, c1g,
                                             bi0, bi1,
                                             Wx0, bx0, Uh0, bh0,
                                             Wx1, bx1, Uh1, bh1);
    }
    // h1(511) is in slot 511&1 = 1
    fc_kernel<<<Bd, 256, 0, stream>>>(h1buf + (size_t)Bd * Hd, fcW, fcb, out);
}

// Round 6
// 24035.791 us; speedup vs baseline: 1.3923x; 1.1969x over previous
//
#include <hip/hip_runtime.h>
#include <math.h>

// ---------------------------------------------------------------------------
// Per-step graph-launched LSTM v6 for MI355X — L2-resident packed f16 weights.
//   B=128, T=512, IN=64, H=1024, 2 layers, head OUT=1 on last step.
//
// vs v5 (28.8 ms = 56 us/step): v5 streamed f32 weights (96 MB/step) from
// MALL every step (per-XCD working set 12 MB >> 4 MB L2). v6 pre-packs all
// weights to f16 (24.5 MB) in per-(col-group, k-chunk) access order; with
// round-robin block->XCD dispatch, each XCD's weight slice is ~3 MB and
// stays L2-resident across all 513 step dispatches.
//
// Step kernel s (s=-1..511): blocks 0..255 layer1(s), blocks 256..511
// layer0(s+1); both read only previous-dispatch state (no grid dependency).
// Intra-block: 8 h-cols (32 gate rows) x 64 batch rows; K split over 8
// waves; LDS atomicAdd reduction; 1 cell/thread; c-state global f32.
// Fallback to the v5 streaming path if ws_size < 28.9 MB.
// ---------------------------------------------------------------------------

#define Hd 1024
#define Bd 128
#define Td 512
#define INd 64

typedef _Float16 f16;
typedef _Float16 half8 __attribute__((ext_vector_type(8)));
typedef float f32x4 __attribute__((ext_vector_type(4)));

__device__ __forceinline__ half8 ldcvt8(const float* p) {
    float4 a = *(const float4*)p;
    float4 b = *(const float4*)(p + 4);
    half8 h;
    h[0] = (f16)a.x; h[1] = (f16)a.y; h[2] = (f16)a.z; h[3] = (f16)a.w;
    h[4] = (f16)b.x; h[5] = (f16)b.y; h[6] = (f16)b.z; h[7] = (f16)b.w;
    return h;
}

// ---------------- init: bi0/bi1, gate biases, zero c and h(-1) slots --------
__global__ __launch_bounds__(512) void init_state(
    const float* __restrict__ bnd, const float* __restrict__ Wb0,
    const float* __restrict__ bb0, const float* __restrict__ Wb1,
    const float* __restrict__ bb1,
    const float* __restrict__ bx0, const float* __restrict__ bh0,
    const float* __restrict__ bx1, const float* __restrict__ bh1,
    float* __restrict__ bi0, float* __restrict__ bi1,
    float* __restrict__ c0g, float* __restrict__ c1g,
    f16* __restrict__ h0buf, f16* __restrict__ h1buf,
    float* __restrict__ gb0, float* __restrict__ gb1)
{
    int idx = blockIdx.x * 512 + threadIdx.x;   // [0, B*H)
    int b = idx >> 10;
    int h = idx & 1023;
    float b0v = bnd[b * 2 + 0], b1v = bnd[b * 2 + 1];
    bi0[idx] = b0v * Wb0[h * 2 + 0] + b1v * Wb0[h * 2 + 1] + bb0[h];
    bi1[idx] = b0v * Wb1[h * 2 + 0] + b1v * Wb1[h * 2 + 1] + bb1[h];
    c0g[idx] = 0.f;
    c1g[idx] = 0.f;
    h0buf[idx + Bd * Hd] = (f16)0.f;   // slot 1 = h(-1)
    h1buf[idx + Bd * Hd] = (f16)0.f;
    if (idx < 4096) {
        gb0[idx] = bx0[idx] + bh0[idx];
        gb1[idx] = bx1[idx] + bh1[idx];
    }
}

// ---------------- pack layer-1 weights: [cg][ch 0..63][j 0..31][q][8] f16 ---
// ch<32: Wx1 k=ch*32+q*8; ch>=32: Uh1 k=(ch-32)*32+q*8. j -> gate j>>3, col j&7.
__global__ __launch_bounds__(512) void pack1(
    const float* __restrict__ Wx1, const float* __restrict__ Uh1,
    f16* __restrict__ W1p)
{
    unsigned i = blockIdx.x * 512 + threadIdx.x;   // unit of 8 f16; 1,048,576
    int cg = i >> 13;
    int rem = i & 8191;
    int ch = rem >> 7;
    int u = rem & 127;
    int j = u >> 2, q = u & 3;
    int row = (j >> 3) * Hd + cg * 8 + (j & 7);
    int kb = ch * 32 + q * 8;
    const float* src = (ch < 32) ? (Wx1 + (size_t)row * Hd + kb)
                                 : (Uh1 + (size_t)row * Hd + (kb - 1024));
    half8 v = ldcvt8(src);
    *(half8*)(W1p + (size_t)i * 8) = v;
}

// ---------------- pack layer-0 weights: Uh0 (32 chunks) + Wx0 (2 chunks) ----
__global__ __launch_bounds__(512) void pack0(
    const float* __restrict__ Uh0, const float* __restrict__ Wx0,
    f16* __restrict__ W0p, f16* __restrict__ Wx0p)
{
    unsigned i = blockIdx.x * 512 + threadIdx.x;   // 524288 + 32768 units
    if (i < 524288u) {
        int cg = i >> 12;
        int rem = i & 4095;
        int ch = rem >> 7;
        int u = rem & 127;
        int j = u >> 2, q = u & 3;
        int row = (j >> 3) * Hd + cg * 8 + (j & 7);
        int kb = ch * 32 + q * 8;
        half8 v = ldcvt8(Uh0 + (size_t)row * Hd + kb);
        *(half8*)(W0p + (size_t)i * 8) = v;
    } else {
        unsigned i2 = i - 524288u;                 // < 32768
        int cg = i2 >> 8;
        int rem = i2 & 255;
        int ch = rem >> 7;                         // 0..1
        int u = rem & 127;
        int j = u >> 2, q = u & 3;
        int row = (j >> 3) * Hd + cg * 8 + (j & 7);
        int kb = ch * 32 + q * 8;                  // 0..63
        half8 v = ldcvt8(Wx0 + (size_t)row * INd + kb);
        *(half8*)(Wx0p + (size_t)i2 * 8) = v;
    }
}

// ---------------- packed step kernel ----------------
__global__ __launch_bounds__(512, 4) void step_packed(
    int s,
    const float* __restrict__ x,     // [B,T,IN] f32
    f16* __restrict__ h0buf, f16* __restrict__ h1buf,
    float* __restrict__ c0g, float* __restrict__ c1g,
    const float* __restrict__ bi0, const float* __restrict__ bi1,
    const f16* __restrict__ W1p, const f16* __restrict__ W0p,
    const f16* __restrict__ Wx0p,
    const float* __restrict__ gb0, const float* __restrict__ gb1)
{
    const int bid = blockIdx.x;
    const bool isL1 = (bid < 256);
    if (isL1 && s < 0) return;
    if (!isL1 && s >= 511) return;

    const int tid  = threadIdx.x;
    const int w    = tid >> 6;
    const int lane = tid & 63;
    const int n    = lane & 15;
    const int q    = lane >> 4;
    const int id2  = isL1 ? bid : bid - 256;
    const int cg   = id2 & 127;
    const int bg   = id2 >> 7;
    const int Rb   = bg * 64;
    const size_t S2 = (size_t)Bd * Hd;

    const f16* h0r = h0buf + (size_t)(s & 1) * S2;          // h0(s)
    const f16* h1r = h1buf + (size_t)((s - 1) & 1) * S2;    // h1(s-1)
    f16* h1w = h1buf + (size_t)(s & 1) * S2;                // h1(s)
    f16* h0w = h0buf + (size_t)((s + 1) & 1) * S2;          // h0(s+1)

    __shared__ float ACC[8][256];
    __shared__ f16 HST[64][8];

    {
        float* az = &ACC[0][0];
        #pragma unroll
        for (int i = 0; i < 4; ++i) az[tid + i * 512] = 0.f;
    }
    __syncthreads();

    f32x4 acc[4][2];
    #pragma unroll
    for (int a = 0; a < 4; ++a) {
        acc[a][0] = (f32x4){0.f, 0.f, 0.f, 0.f};
        acc[a][1] = (f32x4){0.f, 0.f, 0.f, 0.f};
    }

    bool contrib = false;
    if (isL1) {
        // chunks ch = w*8+kk: ch<32 -> Wx1 (A=h0), ch>=32 -> Uh1 (A=h1)
        const f16* hsrc = (w < 4) ? h0r : h1r;
        const f16* wbase = W1p + (size_t)cg * 65536;
        const int akb = (w & 3) * 256;
        #pragma unroll
        for (int kk = 0; kk < 8; ++kk) {
            const int ako = akb + kk * 32 + q * 8;
            const f16* cb = wbase + (size_t)(w * 8 + kk) * 1024;
            half8 Af[4];
            #pragma unroll
            for (int a = 0; a < 4; ++a)
                Af[a] = *(const half8*)(hsrc + (size_t)(Rb + a * 16 + n) * Hd + ako);
            half8 B0 = *(const half8*)(cb + n * 32 + q * 8);
            half8 B1 = *(const half8*)(cb + (16 + n) * 32 + q * 8);
            #pragma unroll
            for (int a = 0; a < 4; ++a) {
                acc[a][0] = __builtin_amdgcn_mfma_f32_16x16x32_f16(Af[a], B0, acc[a][0], 0, 0, 0);
                acc[a][1] = __builtin_amdgcn_mfma_f32_16x16x32_f16(Af[a], B1, acc[a][1], 0, 0, 0);
            }
        }
        contrib = true;
    } else {
        if (w < 4) {
            const f16* wbase = W0p + (size_t)cg * 32768;
            const int akb = w * 256;
            #pragma unroll
            for (int kk = 0; kk < 8; ++kk) {
                const int ako = akb + kk * 32 + q * 8;
                const f16* cb = wbase + (size_t)(w * 8 + kk) * 1024;
                half8 Af[4];
                #pragma unroll
                for (int a = 0; a < 4; ++a)
                    Af[a] = *(const half8*)(h0r + (size_t)(Rb + a * 16 + n) * Hd + ako);
                half8 B0 = *(const half8*)(cb + n * 32 + q * 8);
                half8 B1 = *(const half8*)(cb + (16 + n) * 32 + q * 8);
                #pragma unroll
                for (int a = 0; a < 4; ++a) {
                    acc[a][0] = __builtin_amdgcn_mfma_f32_16x16x32_f16(Af[a], B0, acc[a][0], 0, 0, 0);
                    acc[a][1] = __builtin_amdgcn_mfma_f32_16x16x32_f16(Af[a], B1, acc[a][1], 0, 0, 0);
                }
            }
            contrib = true;
        } else if (w >= 6) {
            const f16* cb = Wx0p + (size_t)cg * 2048 + (size_t)(w - 6) * 1024;
            const int ko = (w - 6) * 32 + q * 8;
            half8 B0 = *(const half8*)(cb + n * 32 + q * 8);
            half8 B1 = *(const half8*)(cb + (16 + n) * 32 + q * 8);
            #pragma unroll
            for (int a = 0; a < 4; ++a) {
                half8 Af = ldcvt8(x + ((size_t)(Rb + a * 16 + n) * Td + (s + 1)) * INd + ko);
                acc[a][0] = __builtin_amdgcn_mfma_f32_16x16x32_f16(Af, B0, acc[a][0], 0, 0, 0);
                acc[a][1] = __builtin_amdgcn_mfma_f32_16x16x32_f16(Af, B1, acc[a][1], 0, 0, 0);
            }
            contrib = true;
        }
    }

    if (contrib) {
        #pragma unroll
        for (int a = 0; a < 4; ++a)
            #pragma unroll
            for (int bt = 0; bt < 2; ++bt)
                #pragma unroll
                for (int r = 0; r < 4; ++r)
                    atomicAdd(&ACC[a * 2 + bt][(q * 4 + r) * 16 + n], acc[a][bt][r]);
    }
    __syncthreads();

    // ---- cell update ----
    {
        const int crow = tid >> 3, ccol = tid & 7;
        const int gR = Rb + crow, gC = cg * 8 + ccol;
        const int ca = crow >> 4, crr = crow & 15;
        const float* gb = isL1 ? gb1 : gb0;
        const float* bi = isL1 ? bi1 : bi0;
        float* cst = isL1 ? c1g : c0g;

        float ip = ACC[ca * 2 + 0][crr * 16 + ccol]     + gb[0 * Hd + gC];
        float fp = ACC[ca * 2 + 0][crr * 16 + 8 + ccol] + gb[1 * Hd + gC]
                 + bi[(size_t)gR * Hd + gC];
        float op = ACC[ca * 2 + 1][crr * 16 + ccol]     + gb[2 * Hd + gC];
        float gp = ACC[ca * 2 + 1][crr * 16 + 8 + ccol] + gb[3 * Hd + gC];
        float I = 1.f / (1.f + expf(-ip));
        float F = 1.f / (1.f + expf(-fp));
        float O = 1.f / (1.f + expf(-op));
        float G = tanhf(gp);
        float c = F * cst[(size_t)gR * Hd + gC] + I * G;
        cst[(size_t)gR * Hd + gC] = c;
        HST[crow][ccol] = (f16)(O * tanhf(c));
    }
    __syncthreads();

    if (tid < 128) {
        int row = tid >> 1, hh = tid & 1;
        unsigned long long v = *(const unsigned long long*)&HST[row][hh * 4];
        f16* dst = (isL1 ? h1w : h0w) + (size_t)(Rb + row) * Hd + cg * 8 + hh * 4;
        *(unsigned long long*)dst = v;
    }
}

// ---------------- legacy (v5) streaming step kernel — ws fallback ----------
__global__ __launch_bounds__(512, 4) void step_legacy(
    int s,
    const float* __restrict__ x,
    f16* __restrict__ h0buf, f16* __restrict__ h1buf,
    float* __restrict__ c0g, float* __restrict__ c1g,
    const float* __restrict__ bi0, const float* __restrict__ bi1,
    const float* __restrict__ Wx0, const float* __restrict__ Uh0,
    const float* __restrict__ Wx1, const float* __restrict__ Uh1,
    const float* __restrict__ gb0, const float* __restrict__ gb1)
{
    const int bid = blockIdx.x;
    const bool isL1 = (bid < 256);
    if (isL1 && s < 0) return;
    if (!isL1 && s >= 511) return;

    const int tid  = threadIdx.x;
    const int w    = tid >> 6;
    const int lane = tid & 63;
    const int n    = lane & 15;
    const int q    = lane >> 4;
    const int id2  = isL1 ? bid : bid - 256;
    const int cg   = id2 & 127;
    const int bg   = id2 >> 7;
    const int Cb   = cg * 8;
    const int Rb   = bg * 64;
    const size_t S2 = (size_t)Bd * Hd;

    const f16* h0r = h0buf + (size_t)(s & 1) * S2;
    const f16* h1r = h1buf + (size_t)((s - 1) & 1) * S2;
    f16* h1w = h1buf + (size_t)(s & 1) * S2;
    f16* h0w = h0buf + (size_t)((s + 1) & 1) * S2;

    __shared__ float ACC[8][256];
    __shared__ f16 HST[64][8];

    int grow[2];
    #pragma unroll
    for (int bt = 0; bt < 2; ++bt) {
        int j = bt * 16 + n;
        grow[bt] = (j >> 3) * Hd + Cb + (j & 7);
    }
    {
        float* az = &ACC[0][0];
        #pragma unroll
        for (int i = 0; i < 4; ++i) az[tid + i * 512] = 0.f;
    }
    __syncthreads();

    f32x4 acc[4][2];
    #pragma unroll
    for (int a = 0; a < 4; ++a) {
        acc[a][0] = (f32x4){0.f, 0.f, 0.f, 0.f};
        acc[a][1] = (f32x4){0.f, 0.f, 0.f, 0.f};
    }

    bool contrib = false;
    if (isL1) {
        const f16*  hsrc = (w < 4) ? h0r : h1r;
        const float* Wsrc = (w < 4) ? Wx1 : Uh1;
        const int kbase = (w & 3) * 256;
        #pragma unroll
        for (int kk = 0; kk < 8; ++kk) {
            const int ko = kbase + kk * 32 + q * 8;
            half8 Af[4];
            #pragma unroll
            for (int a = 0; a < 4; ++a)
                Af[a] = *(const half8*)(hsrc + (size_t)(Rb + a * 16 + n) * Hd + ko);
            half8 B0 = ldcvt8(Wsrc + (size_t)grow[0] * Hd + ko);
            half8 B1 = ldcvt8(Wsrc + (size_t)grow[1] * Hd + ko);
            #pragma unroll
            for (int a = 0; a < 4; ++a) {
                acc[a][0] = __builtin_amdgcn_mfma_f32_16x16x32_f16(Af[a], B0, acc[a][0], 0, 0, 0);
                acc[a][1] = __builtin_amdgcn_mfma_f32_16x16x32_f16(Af[a], B1, acc[a][1], 0, 0, 0);
            }
        }
        contrib = true;
    } else {
        if (w < 4) {
            const int kbase = w * 256;
            #pragma unroll
            for (int kk = 0; kk < 8; ++kk) {
                const int ko = kbase + kk * 32 + q * 8;
                half8 Af[4];
                #pragma unroll
                for (int a = 0; a < 4; ++a)
                    Af[a] = *(const half8*)(h0r + (size_t)(Rb + a * 16 + n) * Hd + ko);
                half8 B0 = ldcvt8(Uh0 + (size_t)grow[0] * Hd + ko);
                half8 B1 = ldcvt8(Uh0 + (size_t)grow[1] * Hd + ko);
                #pragma unroll
                for (int a = 0; a < 4; ++a) {
                    acc[a][0] = __builtin_amdgcn_mfma_f32_16x16x32_f16(Af[a], B0, acc[a][0], 0, 0, 0);
                    acc[a][1] = __builtin_amdgcn_mfma_f32_16x16x32_f16(Af[a], B1, acc[a][1], 0, 0, 0);
                }
            }
            contrib = true;
        } else if (w >= 6) {
            const int ko = (w - 6) * 32 + q * 8;
            half8 B0 = ldcvt8(Wx0 + (size_t)grow[0] * INd + ko);
            half8 B1 = ldcvt8(Wx0 + (size_t)grow[1] * INd + ko);
            #pragma unroll
            for (int a = 0; a < 4; ++a) {
                half8 Af = ldcvt8(x + ((size_t)(Rb + a * 16 + n) * Td + (s + 1)) * INd + ko);
                acc[a][0] = __builtin_amdgcn_mfma_f32_16x16x32_f16(Af, B0, acc[a][0], 0, 0, 0);
                acc[a][1] = __builtin_amdgcn_mfma_f32_16x16x32_f16(Af, B1, acc[a][1], 0, 0, 0);
            }
            contrib = true;
        }
    }

    if (contrib) {
        #pragma unroll
        for (int a = 0; a < 4; ++a)
            #pragma unroll
            for (int bt = 0; bt < 2; ++bt)
                #pragma unroll
                for (int r = 0; r < 4; ++r)
                    atomicAdd(&ACC[a * 2 + bt][(q * 4 + r) * 16 + n], acc[a][bt][r]);
    }
    __syncthreads();

    {
        const int crow = tid >> 3, ccol = tid & 7;
        const int gR = Rb + crow, gC = Cb + ccol;
        const int ca = crow >> 4, crr = crow & 15;
        const float* gb = isL1 ? gb1 : gb0;
        const float* bi = isL1 ? bi1 : bi0;
        float* cst = isL1 ? c1g : c0g;

        float ip = ACC[ca * 2 + 0][crr * 16 + ccol]     + gb[0 * Hd + gC];
        float fp = ACC[ca * 2 + 0][crr * 16 + 8 + ccol] + gb[1 * Hd + gC]
                 + bi[(size_t)gR * Hd + gC];
        float op = ACC[ca * 2 + 1][crr * 16 + ccol]     + gb[2 * Hd + gC];
        float gp = ACC[ca * 2 + 1][crr * 16 + 8 + ccol] + gb[3 * Hd + gC];
        float I = 1.f / (1.f + expf(-ip));
        float F = 1.f / (1.f + expf(-fp));
        float O = 1.f / (1.f + expf(-op));
        float G = tanhf(gp);
        float c = F * cst[(size_t)gR * Hd + gC] + I * G;
        cst[(size_t)gR * Hd + gC] = c;
        HST[crow][ccol] = (f16)(O * tanhf(c));
    }
    __syncthreads();

    if (tid < 128) {
        int row = tid >> 1, hh = tid & 1;
        unsigned long long v = *(const unsigned long long*)&HST[row][hh * 4];
        f16* dst = (isL1 ? h1w : h0w) + (size_t)(Rb + row) * Hd + Cb + hh * 4;
        *(unsigned long long*)dst = v;
    }
}

// ---------------- fc head ----------------
__global__ __launch_bounds__(256) void fc_kernel(
    const f16* __restrict__ h1, const float* __restrict__ fcW,
    const float* __restrict__ fcb, float* __restrict__ out)
{
    int b = blockIdx.x;
    int tid = threadIdx.x;
    const f16* hrow = h1 + (size_t)b * Hd + tid * 4;
    const float* fw = fcW + tid * 4;
    float sum = (float)hrow[0] * fw[0] + (float)hrow[1] * fw[1]
              + (float)hrow[2] * fw[2] + (float)hrow[3] * fw[3];
    #pragma unroll
    for (int off = 32; off > 0; off >>= 1) sum += __shfl_down(sum, off, 64);
    __shared__ float ls[4];
    if ((tid & 63) == 0) ls[tid >> 6] = sum;
    __syncthreads();
    if (tid == 0) out[b] = ls[0] + ls[1] + ls[2] + ls[3] + fcb[0];
}

// ---------------------------------------------------------------------------
extern "C" void kernel_launch(void* const* d_in, const int* in_sizes, int n_in,
                              void* d_out, int out_size, void* d_ws, size_t ws_size,
                              hipStream_t stream) {
    const float* x        = (const float*)d_in[0];
    const float* boundary = (const float*)d_in[1];
    const float* Wx0      = (const float*)d_in[2];
    const float* bx0      = (const float*)d_in[3];
    const float* Uh0      = (const float*)d_in[4];
    const float* bh0      = (const float*)d_in[5];
    const float* Wb0      = (const float*)d_in[6];
    const float* bb0      = (const float*)d_in[7];
    const float* Wx1      = (const float*)d_in[8];
    const float* bx1      = (const float*)d_in[9];
    const float* Uh1      = (const float*)d_in[10];
    const float* bh1      = (const float*)d_in[11];
    const float* Wb1      = (const float*)d_in[12];
    const float* bb1      = (const float*)d_in[13];
    const float* fcW      = (const float*)d_in[14];
    const float* fcb      = (const float*)d_in[15];
    float* out = (float*)d_out;

    char* ws = (char*)d_ws;
    const size_t WS_NEEDED = 28868608;   // 27.5 MB packed layout

    if (ws_size >= WS_NEEDED) {
        f16*   W1p   = (f16*)(ws);                    // 16 MB
        f16*   W0p   = (f16*)(ws + 16777216);         //  8 MB
        f16*   Wx0p  = (f16*)(ws + 25165824);         //  0.5 MB
        f16*   h0buf = (f16*)(ws + 25690112);         //  512 KB (2 slots)
        f16*   h1buf = (f16*)(ws + 26214400);         //  512 KB
        float* c0g   = (float*)(ws + 26738688);       //  512 KB
        float* c1g   = (float*)(ws + 27262976);       //  512 KB
        float* bi0   = (float*)(ws + 27787264);       //  512 KB
        float* bi1   = (float*)(ws + 28311552);       //  512 KB
        float* gb0   = (float*)(ws + 28835840);       //   16 KB
        float* gb1   = (float*)(ws + 28852224);       //   16 KB

        init_state<<<256, 512, 0, stream>>>(boundary, Wb0, bb0, Wb1, bb1,
                                            bx0, bh0, bx1, bh1,
                                            bi0, bi1, c0g, c1g, h0buf, h1buf,
                                            gb0, gb1);
        pack1<<<2048, 512, 0, stream>>>(Wx1, Uh1, W1p);
        pack0<<<1088, 512, 0, stream>>>(Uh0, Wx0, W0p, Wx0p);

        for (int s = -1; s <= 511; ++s)
            step_packed<<<512, 512, 0, stream>>>(s, x, h0buf, h1buf, c0g, c1g,
                                                 bi0, bi1, W1p, W0p, Wx0p,
                                                 gb0, gb1);
        fc_kernel<<<Bd, 256, 0, stream>>>(h1buf + (size_t)Bd * Hd, fcW, fcb, out);
    } else {
        f16*   h0buf = (f16*)(ws);                    // 512 KB
        f16*   h1buf = (f16*)(ws + 524288);           // 512 KB
        float* c0g   = (float*)(ws + 1048576);
        float* c1g   = (float*)(ws + 1572864);
        float* bi0   = (float*)(ws + 2097152);
        float* bi1   = (float*)(ws + 2621440);
        float* gb0   = (float*)(ws + 3145728);
        float* gb1   = (float*)(ws + 3162112);

        init_state<<<256, 512, 0, stream>>>(boundary, Wb0, bb0, Wb1, bb1,
                                            bx0, bh0, bx1, bh1,
                                            bi0, bi1, c0g, c1g, h0buf, h1buf,
                                            gb0, gb1);
        for (int s = -1; s <= 511; ++s)
            step_legacy<<<512, 512, 0, stream>>>(s, x, h0buf, h1buf, c0g, c1g,
                                                 bi0, bi1, Wx0, Uh0, Wx1, Uh1,
                                                 gb0, gb1);
        fc_kernel<<<Bd, 256, 0, stream>>>(h1buf + (size_t)Bd * Hd, fcW, fcb, out);
    }
}